// Round 1
// 807.805 us; speedup vs baseline: 1.0793x; 1.0793x over previous
//
#include <hip/hip_runtime.h>
#include <hip/hip_bf16.h>
#include <math.h>

typedef unsigned short u16;
typedef __attribute__((ext_vector_type(8))) __bf16 bf16x8;
typedef __attribute__((ext_vector_type(4))) float f32x4;

__device__ __forceinline__ u16 f2b(float f) {
  unsigned u = __builtin_bit_cast(unsigned, f);
  u += 0x7fffu + ((u >> 16) & 1u);
  return (u16)(u >> 16);
}
__device__ __forceinline__ float b2f(u16 h) {
  unsigned u = ((unsigned)h) << 16;
  return __builtin_bit_cast(float, u);
}

__device__ __forceinline__ void gld_lds16(const u16* g, u16* l) {
  __builtin_amdgcn_global_load_lds(
      (const __attribute__((address_space(1))) unsigned int*)g,
      (__attribute__((address_space(3))) unsigned int*)l, 16, 0, 0);
}

#define MFMA16(a, b, c) \
  c = __builtin_amdgcn_mfma_f32_16x16x32_bf16(a, b, c, 0, 0, 0)

// ---------------- 128x128 BT-form GEMM tile body (m97 structure) -----------
// kept for k_score (288 tiles -> bad 256^2 grid tail; 128^2 wins there)
template <class FC>
__device__ __forceinline__ void gemm128_body(const u16* A, int lda,
                                             const u16* B, int ldb, FC fc,
                                             int m0, int n0, int K) {
  __shared__ __align__(16) u16 As[128 * 64];
  __shared__ __align__(16) u16 Bs[128 * 64];
  const int tid = threadIdx.x;
  const int wave = tid >> 6;
  const int lane = tid & 63;
  const int srow = lane >> 3;
  const int scol = ((lane & 7) ^ srow) * 8;
  const int wm = (wave & 1) * 64;
  const int wn = (wave >> 1) * 64;
  const int fm = lane & 15;
  const int fs = fm & 7;

  const u16* Abase = A + (size_t)m0 * lda;
  const u16* Bbase = B + (size_t)n0 * ldb;
  const size_t aLane = (size_t)(wave * 8 + srow) * lda + scol;
  const size_t bLane = (size_t)(wave * 8 + srow) * ldb + scol;

  f32x4 acc[4][4];
#pragma unroll
  for (int i = 0; i < 4; ++i)
#pragma unroll
    for (int j = 0; j < 4; ++j) acc[i][j] = (f32x4){0.f, 0.f, 0.f, 0.f};

  for (int k0 = 0; k0 < K; k0 += 64) {
#pragma unroll
    for (int c = 0; c < 4; ++c) {
      gld_lds16(Abase + (aLane + (size_t)(c * 32) * lda + k0),
                &As[(c * 4 + wave) * 512]);
      gld_lds16(Bbase + (bLane + (size_t)(c * 32) * ldb + k0),
                &Bs[(c * 4 + wave) * 512]);
    }
    __syncthreads();
#pragma unroll
    for (int kk = 0; kk < 2; ++kk) {
      const int cb = kk * 4 + (lane >> 4);
      const int p8 = (cb ^ fs) * 8;
      bf16x8 af[4], bfr[4];
#pragma unroll
      for (int i = 0; i < 4; ++i)
        af[i] = *(const bf16x8*)&As[(wm + i * 16 + fm) * 64 + p8];
#pragma unroll
      for (int j = 0; j < 4; ++j)
        bfr[j] = *(const bf16x8*)&Bs[(wn + j * 16 + fm) * 64 + p8];
#pragma unroll
      for (int i = 0; i < 4; ++i)
#pragma unroll
        for (int j = 0; j < 4; ++j) MFMA16(af[i], bfr[j], acc[i][j]);
    }
    __syncthreads();
  }
  const int er = lane >> 4;
#pragma unroll
  for (int i = 0; i < 4; ++i)
#pragma unroll
    for (int j = 0; j < 4; ++j)
#pragma unroll
      for (int r = 0; r < 4; ++r) {
        int m = m0 + wm + i * 16 + er * 4 + r;
        int n = n0 + wn + j * 16 + fm;
        fc(m, n, acc[i][j][r]);
      }
}

// ---------------- 256x256 8-phase BT-form GEMM body (T2+T3+T4+T5) ----------
// 512 thr = 8 waves (2M x 4N), per-wave 128x64 out, BK=64, LDS 128KiB dbuf.
// Schedule (group T computes K-tile T from buf=T&1, k0=T*64):
//   ph0: ds_read A@kk0 (8) + B@kk0,kk1 (8); stage KT(T+1).A.h1 -> As[!buf]
//        bar; lgkm0; prio1; 16 MFMA (n0,n1 x kk0); prio0; bar
//   ph1: stage KT(T+2).B.h0 -> Bs[buf]   (Bs[buf] fully read at ph0)
//        bar; prio1; 16 MFMA (n2,n3 x kk0); prio0; bar
//   ph2: ds_read A@kk1 (8); stage KT(T+2).B.h1 -> Bs[buf]
//        bar; lgkm0; prio1; 16 MFMA (n0,n1 x kk1); prio0; bar
//   ph3: stage KT(T+2).A.h0 -> As[buf]   (As[buf] reads done at ph2)
//        bar; prio1; 16 MFMA (n2,n3 x kk1); prio0; vmcnt(6); bar
// Steady state leaves exactly 3 half-tiles (6 loads) in flight across the
// group boundary -> vmcnt(6), never 0 in the main loop. Requires nkt >= 3.
template <class FC>
__device__ __forceinline__ void gemm256_body(const u16* A, int lda,
                                             const u16* B, int ldb, FC fc,
                                             int m0, int n0, int K) {
  __shared__ __align__(16) u16 As[2][16384];
  __shared__ __align__(16) u16 Bs[2][16384];
  const int tid = threadIdx.x;
  const int wave = tid >> 6;
  const int lane = tid & 63;
  const int wr = wave >> 2;  // 0..1 (M)
  const int wc = wave & 3;   // 0..3 (N)
  const int fm = lane & 15;
  const int cb4 = lane >> 4;  // 0..3
  const int fs = fm & 7;
  const int srow = lane >> 3;
  const int scol = ((lane & 7) ^ srow) * 8;  // inverse-swizzled global col

  const u16* Ab = A + (size_t)(m0 + srow) * lda + scol;
  const u16* Bb = B + (size_t)(n0 + srow) * ldb + scol;

  const int paRow = (wr * 128 + fm) * 64;
  const int pbRow = (wc * 64 + fm) * 64;
  const int q0 = (cb4 ^ fs) * 8;  // phys chunk offset, kk0
  const int q1 = q0 ^ 32;         // kk1 ( (4+cb4)^fs == (cb4^fs)^4 )

  f32x4 acc[8][4];
#pragma unroll
  for (int m = 0; m < 8; ++m)
#pragma unroll
    for (int n = 0; n < 4; ++n) acc[m][n] = (f32x4){0.f, 0.f, 0.f, 0.f};

  // stage one half-tile piece: wave covers chunks {wave, wave+8} of 16
  auto stA = [&](int bi, int h, int kg) {
    const u16* g = Ab + (size_t)(h * 128 + wave * 8) * lda + kg;
    gld_lds16(g, &As[bi][h * 8192 + wave * 512]);
    gld_lds16(g + (size_t)64 * lda, &As[bi][h * 8192 + (wave + 8) * 512]);
  };
  auto stB = [&](int bi, int h, int kg) {
    const u16* g = Bb + (size_t)(h * 128 + wave * 8) * ldb + kg;
    gld_lds16(g, &Bs[bi][h * 8192 + wave * 512]);
    gld_lds16(g + (size_t)64 * ldb, &Bs[bi][h * 8192 + (wave + 8) * 512]);
  };

  const int nkt = K >> 6;  // call sites guarantee nkt >= 4

  // prologue: KT0 fully + KT1.{B.h0,B.h1,A.h0}; leave KT1 trio in flight
  stB(0, 0, 0);
  stB(0, 1, 0);
  stA(0, 0, 0);
  stA(0, 1, 0);
  stB(1, 0, 64);
  stB(1, 1, 64);
  stA(1, 0, 64);
  asm volatile("s_waitcnt vmcnt(6)" ::: "memory");
  __builtin_amdgcn_s_barrier();

  int buf = 0;
  for (int T = 0; T < nkt; ++T, buf ^= 1) {
    const int kc = T * 64;
    const bool sA1 = (T + 1) < nkt;
    const bool sN2 = (T + 2) < nkt;
    bf16x8 af[8], bv[4][2];
    // ---- ph0
#pragma unroll
    for (int m = 0; m < 8; ++m)
      af[m] = *(const bf16x8*)&As[buf][paRow + m * 1024 + q0];
#pragma unroll
    for (int n = 0; n < 4; ++n) {
      bv[n][0] = *(const bf16x8*)&Bs[buf][pbRow + n * 1024 + q0];
      bv[n][1] = *(const bf16x8*)&Bs[buf][pbRow + n * 1024 + q1];
    }
    if (sA1) stA(buf ^ 1, 1, kc + 64);
    __builtin_amdgcn_s_barrier();
    asm volatile("s_waitcnt lgkmcnt(0)" ::: "memory");
    __builtin_amdgcn_sched_barrier(0);
    __builtin_amdgcn_s_setprio(1);
#pragma unroll
    for (int m = 0; m < 8; ++m) {
      MFMA16(af[m], bv[0][0], acc[m][0]);
      MFMA16(af[m], bv[1][0], acc[m][1]);
    }
    __builtin_amdgcn_s_setprio(0);
    __builtin_amdgcn_s_barrier();
    // ---- ph1
    if (sN2) stB(buf, 0, kc + 128);
    __builtin_amdgcn_s_barrier();
    __builtin_amdgcn_s_setprio(1);
#pragma unroll
    for (int m = 0; m < 8; ++m) {
      MFMA16(af[m], bv[2][0], acc[m][2]);
      MFMA16(af[m], bv[3][0], acc[m][3]);
    }
    __builtin_amdgcn_s_setprio(0);
    __builtin_amdgcn_s_barrier();
    // ---- ph2
#pragma unroll
    for (int m = 0; m < 8; ++m)
      af[m] = *(const bf16x8*)&As[buf][paRow + m * 1024 + q1];
    if (sN2) stB(buf, 1, kc + 128);
    __builtin_amdgcn_s_barrier();
    asm volatile("s_waitcnt lgkmcnt(0)" ::: "memory");
    __builtin_amdgcn_sched_barrier(0);
    __builtin_amdgcn_s_setprio(1);
#pragma unroll
    for (int m = 0; m < 8; ++m) {
      MFMA16(af[m], bv[0][1], acc[m][0]);
      MFMA16(af[m], bv[1][1], acc[m][1]);
    }
    __builtin_amdgcn_s_setprio(0);
    __builtin_amdgcn_s_barrier();
    // ---- ph3
    if (sN2) stA(buf, 0, kc + 128);
    __builtin_amdgcn_s_barrier();
    __builtin_amdgcn_s_setprio(1);
#pragma unroll
    for (int m = 0; m < 8; ++m) {
      MFMA16(af[m], bv[2][1], acc[m][2]);
      MFMA16(af[m], bv[3][1], acc[m][3]);
    }
    __builtin_amdgcn_s_setprio(0);
    if (sN2) {
      asm volatile("s_waitcnt vmcnt(6)" ::: "memory");
    } else if (sA1) {
      asm volatile("s_waitcnt vmcnt(0)" ::: "memory");
    }
    __builtin_amdgcn_s_barrier();
  }

  const int er = lane >> 4;
#pragma unroll
  for (int m = 0; m < 8; ++m)
#pragma unroll
    for (int n = 0; n < 4; ++n)
#pragma unroll
      for (int r = 0; r < 4; ++r)
        fc(m0 + wr * 128 + m * 16 + er * 4 + r, n0 + wc * 64 + n * 16 + fm,
           acc[m][n][r]);
}

// ---------------- epilogue functors ----------------
struct EQKV {
  u16* qb;
  u16* kb;
  float* vout;
  const float* bias;
  __device__ __forceinline__ void operator()(int m, int n, float v) const {
    v += bias[n];
    int b = m >> 11, l = m & 2047;
    int part = n >> 11, nn = n & 2047, h = nn >> 10, d = nn & 1023;
    size_t idx = ((size_t)((b << 1) + h) * 2048 + l) * 1024 + d;
    if (part == 0)
      qb[idx] = f2b(v);
    else if (part == 1)
      kb[idx] = f2b(v);
    else
      vout[idx] = v;
  }
};
struct EScoreB {
  u16* S;
  __device__ __forceinline__ void operator()(int m, int n, float v) const {
    S[((size_t)m << 11) + n] = f2b(v * 0.03125f + (n > m ? -1.0e9f : 0.0f));
  }
};
struct EBf16 {
  u16* o;
  int ld;
  __device__ __forceinline__ void operator()(int m, int n, float v) const {
    o[(size_t)m * ld + n] = f2b(v);
  }
};
struct EOut {
  float* o;
  const float* bias;
  __device__ __forceinline__ void operator()(int m, int n, float v) const {
    o[((size_t)m << 11) + n] = v + bias[n];
  }
};

__device__ __forceinline__ u16* spz(u16* sp0, u16* sp1, int z) {
  return (z < 4) ? sp0 + (size_t)z * 4194304 : sp1 + (size_t)(z - 4) * 4194304;
}

// ---------------- kernels ----------------
__global__ void __launch_bounds__(256) k_cast3(const float* x, const float* w1,
                                               const float* w2, u16* xb,
                                               u16* w1b, u16* w2b) {
  long i = (long)(blockIdx.x * 256 + threadIdx.x) * 4;
  const float* src;
  u16* dst;
  long off;
  if (i < 16777216L) {
    src = x; dst = xb; off = i;
  } else if (i < 16777216L + 12582912L) {
    src = w1; dst = w1b; off = i - 16777216L;
  } else {
    src = w2; dst = w2b; off = i - 16777216L - 12582912L;
  }
  float4 f = *(const float4*)(src + off);
  ushort4 o;
  o.x = f2b(f.x);
  o.y = f2b(f.y);
  o.z = f2b(f.z);
  o.w = f2b(f.w);
  *(ushort4*)(dst + off) = o;
}

__global__ void __launch_bounds__(512, 2) k_qkv(const u16* xb, const u16* wb,
                                                const float* bias, u16* qb,
                                                u16* kb, float* vout) {
  gemm256_body(xb, 2048, wb, 2048, EQKV{qb, kb, vout, bias}, blockIdx.y * 256,
               blockIdx.x * 256, 2048);
}

__global__ void __launch_bounds__(256) k_rope(u16* qb, u16* kb, float* kout) {
  int l = blockIdx.x;
  int t = threadIdx.x;
  float lf = (float)l;
  const float c0 = (float)(-9.210340371976184 / 1024.0);
  float s0, c_0, s1, c_1;
  {
    float inv = __expf((float)(2 * t) * c0);
    __sincosf(lf * inv, &s0, &c_0);
    float inv2 = __expf((float)(2 * (t + 256)) * c0);
    __sincosf(lf * inv2, &s1, &c_1);
  }
#pragma unroll
  for (int bh = 0; bh < 8; ++bh) {
    size_t base = ((size_t)bh * 2048 + l) * 1024;
#pragma unroll
    for (int half = 0; half < 2; ++half) {
      int i = t + half * 256;
      float c = half ? c_1 : c_0;
      float s = half ? s1 : s0;
      float x1 = b2f(qb[base + i]), x2 = b2f(qb[base + 512 + i]);
      qb[base + i] = f2b(x1 * c - x2 * s);
      qb[base + 512 + i] = f2b(x1 * s + x2 * c);
      float y1 = b2f(kb[base + i]), y2 = b2f(kb[base + 512 + i]);
      float r1 = y1 * c - y2 * s, r2 = y1 * s + y2 * c;
      kb[base + i] = f2b(r1);
      kb[base + 512 + i] = f2b(r2);
      kout[base + i] = r1;
      kout[base + 512 + i] = r2;
    }
  }
}

__global__ void __launch_bounds__(256) k_transpose_v(const float* v, u16* vt) {
  __shared__ u16 tile[64][65];
  int bh = blockIdx.z;
  int d0 = blockIdx.x * 64, l0 = blockIdx.y * 64;
  const float* vb = v + (size_t)bh * 2048 * 1024;
  u16* vtb = vt + (size_t)bh * 1024 * 2048;
  int t = threadIdx.x;
  int c = t & 63, r4 = t >> 6;
#pragma unroll
  for (int r = 0; r < 16; ++r) {
    int row = r * 4 + r4;
    tile[row][c] = f2b(vb[(size_t)(l0 + row) * 1024 + d0 + c]);
  }
  __syncthreads();
#pragma unroll
  for (int r = 0; r < 16; ++r) {
    int drow = r * 4 + r4;
    vtb[(size_t)(d0 + drow) * 2048 + l0 + c] = tile[c][drow];
  }
}

__global__ void __launch_bounds__(256) k_score(const u16* qb, const u16* kb,
                                               u16* sp0, u16* sp1) {
  int m0 = blockIdx.y * 128, n0 = blockIdx.x * 128;
  if (n0 > m0) return;
  int z = blockIdx.z;
  const u16* q = qb + (size_t)z * 2048 * 1024;
  const u16* k = kb + (size_t)z * 2048 * 1024;
  gemm128_body(q, 1024, k, 1024, EScoreB{spz(sp0, sp1, z)}, m0, n0, 1024);
}

// in-place softmax; writes probs zero-padded out to a 256-col boundary so
// k_pv's 256-row tiles (Keff = m0+256) read fully-defined P everywhere.
__global__ void __launch_bounds__(256) k_softmax(u16* sp0, u16* sp1) {
  int l = blockIdx.x, z = blockIdx.y;
  u16* row = spz(sp0, sp1, z) + ((size_t)l << 11);
  int t = threadIdx.x;
  int jend = ((l >> 8) + 1) << 8;  // 256-granule (was 128)
  __shared__ float red[4];
  float vals[8];
  float mx = -1e30f;
#pragma unroll
  for (int i = 0; i < 8; ++i) {
    int j = i * 256 + t;
    float v = (j <= l) ? b2f(row[j]) : -1e30f;
    vals[i] = v;
    mx = fmaxf(mx, v);
  }
#pragma unroll
  for (int off = 32; off; off >>= 1) mx = fmaxf(mx, __shfl_down(mx, off));
  if ((t & 63) == 0) red[t >> 6] = mx;
  __syncthreads();
  mx = fmaxf(fmaxf(red[0], red[1]), fmaxf(red[2], red[3]));
  __syncthreads();
  float sum = 0.f;
#pragma unroll
  for (int i = 0; i < 8; ++i) {
    int j = i * 256 + t;
    float e = (j <= l) ? __expf(vals[i] - mx) : 0.f;
    vals[i] = e;
    sum += e;
  }
#pragma unroll
  for (int off = 32; off; off >>= 1) sum += __shfl_down(sum, off);
  if ((t & 63) == 0) red[t >> 6] = sum;
  __syncthreads();
  sum = red[0] + red[1] + red[2] + red[3];
  float is = 1.0f / sum;
#pragma unroll
  for (int i = 0; i < 8; ++i) {
    int j = i * 256 + t;
    if (j < jend) row[j] = f2b(vals[i] * is);
  }
}

__global__ void __launch_bounds__(512, 2) k_pv(u16* sp0, u16* sp1,
                                               const u16* vt, u16* vh) {
  int z = blockIdx.z;
  int b = z >> 1, h = z & 1;
  int m0 = blockIdx.y * 256, n0 = blockIdx.x * 256;
  const u16* Pz = spz(sp0, sp1, z);
  const u16* vtb = vt + (size_t)z * 1024 * 2048;
  u16* outb = vh + (size_t)b * 2048 * 2048 + (size_t)h * 1024;
  int Keff = m0 + 256;  // causal: P zero-padded to 256 boundary by k_softmax
  gemm256_body(Pz, 2048, vtb, 2048, EBf16{outb, 2048}, m0, n0, Keff);
}

__global__ void __launch_bounds__(512, 2) k_out(const u16* vh, const u16* w2,
                                                const float* bias, float* out) {
  gemm256_body(vh, 2048, w2, 2048, EOut{out, bias}, blockIdx.y * 256,
               blockIdx.x * 256, 2048);
}

// ---------------- launch ----------------
extern "C" void kernel_launch(void* const* d_in, const int* in_sizes, int n_in,
                              void* d_out, int out_size, void* d_ws,
                              size_t ws_size, hipStream_t stream) {
  const float* x = (const float*)d_in[0];
  const float* w1 = (const float*)d_in[2];
  const float* b1 = (const float*)d_in[3];
  const float* w2 = (const float*)d_in[4];
  const float* b2 = (const float*)d_in[5];
  float* out = (float*)d_out;
  float* kout = out + (size_t)16777216;
  float* vout = kout + (size_t)16777216;

  char* ws = (char*)d_ws;
  u16* xb = (u16*)ws;
  ws += (size_t)33554432;
  u16* w1b = (u16*)ws;
  ws += (size_t)25165824;
  u16* w2b = (u16*)ws;
  ws += (size_t)8388608;
  u16* qb = (u16*)ws;
  ws += (size_t)33554432;
  u16* kb = (u16*)ws;
  ws += (size_t)33554432;
  u16* vtb = (u16*)ws;
  ws += (size_t)33554432;
  u16* sp1 = (u16*)ws;
  u16* sp0 = xb;
  u16* vh = qb;

  k_cast3<<<32768, 256, 0, stream>>>(x, w1, w2, xb, w1b, w2b);
  k_qkv<<<dim3(24, 32), 512, 0, stream>>>(xb, w1b, b1, qb, kb, vout);
  k_rope<<<2048, 256, 0, stream>>>(qb, kb, kout);
  k_transpose_v<<<dim3(16, 32, 8), 256, 0, stream>>>(vout, vtb);
  k_score<<<dim3(16, 16, 8), 256, 0, stream>>>(qb, kb, sp0, sp1);
  k_softmax<<<dim3(2048, 8), 256, 0, stream>>>(sp0, sp1);
  k_pv<<<dim3(4, 8, 8), 512, 0, stream>>>(sp0, sp1, vtb, vh);
  k_out<<<dim3(8, 32), 512, 0, stream>>>(vh, w2b, b2, out);
}

// Round 2
// 807.664 us; speedup vs baseline: 1.0795x; 1.0002x over previous
//
#include <hip/hip_runtime.h>
#include <hip/hip_bf16.h>
#include <math.h>

typedef unsigned short u16;
typedef __attribute__((ext_vector_type(8))) __bf16 bf16x8;
typedef __attribute__((ext_vector_type(4))) float f32x4;

__device__ __forceinline__ u16 f2b(float f) {
  unsigned u = __builtin_bit_cast(unsigned, f);
  u += 0x7fffu + ((u >> 16) & 1u);
  return (u16)(u >> 16);
}
__device__ __forceinline__ float b2f(u16 h) {
  unsigned u = ((unsigned)h) << 16;
  return __builtin_bit_cast(float, u);
}

__device__ __forceinline__ void gld_lds16(const u16* g, u16* l) {
  __builtin_amdgcn_global_load_lds(
      (const __attribute__((address_space(1))) unsigned int*)g,
      (__attribute__((address_space(3))) unsigned int*)l, 16, 0, 0);
}

#define MFMA16(a, b, c) \
  c = __builtin_amdgcn_mfma_f32_16x16x32_bf16(a, b, c, 0, 0, 0)

// ---------------- 128x128 BT-form GEMM tile body (m97 structure) -----------
// kept for k_score (288 tiles -> bad 256^2 grid tail; 128^2 wins there)
template <class FC>
__device__ __forceinline__ void gemm128_body(const u16* A, int lda,
                                             const u16* B, int ldb, FC fc,
                                             int m0, int n0, int K) {
  __shared__ __align__(16) u16 As[128 * 64];
  __shared__ __align__(16) u16 Bs[128 * 64];
  const int tid = threadIdx.x;
  const int wave = tid >> 6;
  const int lane = tid & 63;
  const int srow = lane >> 3;
  const int scol = ((lane & 7) ^ srow) * 8;
  const int wm = (wave & 1) * 64;
  const int wn = (wave >> 1) * 64;
  const int fm = lane & 15;
  const int fs = fm & 7;

  const u16* Abase = A + (size_t)m0 * lda;
  const u16* Bbase = B + (size_t)n0 * ldb;
  const size_t aLane = (size_t)(wave * 8 + srow) * lda + scol;
  const size_t bLane = (size_t)(wave * 8 + srow) * ldb + scol;

  f32x4 acc[4][4];
#pragma unroll
  for (int i = 0; i < 4; ++i)
#pragma unroll
    for (int j = 0; j < 4; ++j) acc[i][j] = (f32x4){0.f, 0.f, 0.f, 0.f};

  for (int k0 = 0; k0 < K; k0 += 64) {
#pragma unroll
    for (int c = 0; c < 4; ++c) {
      gld_lds16(Abase + (aLane + (size_t)(c * 32) * lda + k0),
                &As[(c * 4 + wave) * 512]);
      gld_lds16(Bbase + (bLane + (size_t)(c * 32) * ldb + k0),
                &Bs[(c * 4 + wave) * 512]);
    }
    __syncthreads();
#pragma unroll
    for (int kk = 0; kk < 2; ++kk) {
      const int cb = kk * 4 + (lane >> 4);
      const int p8 = (cb ^ fs) * 8;
      bf16x8 af[4], bfr[4];
#pragma unroll
      for (int i = 0; i < 4; ++i)
        af[i] = *(const bf16x8*)&As[(wm + i * 16 + fm) * 64 + p8];
#pragma unroll
      for (int j = 0; j < 4; ++j)
        bfr[j] = *(const bf16x8*)&Bs[(wn + j * 16 + fm) * 64 + p8];
#pragma unroll
      for (int i = 0; i < 4; ++i)
#pragma unroll
        for (int j = 0; j < 4; ++j) MFMA16(af[i], bfr[j], acc[i][j]);
    }
    __syncthreads();
  }
  const int er = lane >> 4;
#pragma unroll
  for (int i = 0; i < 4; ++i)
#pragma unroll
    for (int j = 0; j < 4; ++j)
#pragma unroll
      for (int r = 0; r < 4; ++r) {
        int m = m0 + wm + i * 16 + er * 4 + r;
        int n = n0 + wn + j * 16 + fm;
        fc(m, n, acc[i][j][r]);
      }
}

// ---------------- 256x256 3-barrier BT-form GEMM body ----------------------
// 512 thr = 8 waves (2M x 4N), per-wave 128x64 out, BK=64, LDS 128KiB dbuf.
// Per K-tile T (buf = T&1, kc = T*64), THREE barriers (hazard-minimal):
//   P0: ds_read af@q0 (8) + bv q0,q1 (8); stage KT(T+1).A.h1 -> As[!buf]
//       lgkm0; prio1; 8x[4 MFMA q0 ; ds_read ag@q1]  (SGB-pinned); prio0
//       BAR   <- publishes: all B-reads + A@q0/q1-reads of Bs[buf]/As[buf] done
//   P1: stage KT(T+2).B.h0/h1 -> Bs[buf]  (safe: Bs[buf] fully read at P0)
//       lgkm0 (ag reads serviced under P0 MFMA); prio1; 32 MFMA q1; prio0
//       BAR   <- publishes: As[buf] fully read
//   P2: stage KT(T+2).A.h0 -> As[buf]; vmcnt(6)  (waits KT+1 landed, leaves
//       KT+2 trio in flight); BAR <- publishes KT+1 LDS data for T+1's reads
// Redundant pre-MFMA barriers removed: each wave's lgkm0 precedes its
// trailing barrier, so read-completion is already published per phase.
template <class FC>
__device__ __forceinline__ void gemm256_body(const u16* A, int lda,
                                             const u16* B, int ldb, FC fc,
                                             int m0, int n0, int K) {
  __shared__ __align__(16) u16 As[2][16384];
  __shared__ __align__(16) u16 Bs[2][16384];
  const int tid = threadIdx.x;
  const int wave = tid >> 6;
  const int lane = tid & 63;
  const int wr = wave >> 2;  // 0..1 (M)
  const int wc = wave & 3;   // 0..3 (N)
  const int fm = lane & 15;
  const int cb4 = lane >> 4;  // 0..3
  const int fs = fm & 7;
  const int srow = lane >> 3;
  const int scol = ((lane & 7) ^ srow) * 8;  // inverse-swizzled global col

  const u16* Ab = A + (size_t)(m0 + srow) * lda + scol;
  const u16* Bb = B + (size_t)(n0 + srow) * ldb + scol;

  const int paRow = (wr * 128 + fm) * 64;
  const int pbRow = (wc * 64 + fm) * 64;
  const int q0 = (cb4 ^ fs) * 8;  // phys chunk offset, kk0
  const int q1 = q0 ^ 32;         // kk1 ( (4+cb4)^fs == (cb4^fs)^4 )

  f32x4 acc[8][4];
#pragma unroll
  for (int m = 0; m < 8; ++m)
#pragma unroll
    for (int n = 0; n < 4; ++n) acc[m][n] = (f32x4){0.f, 0.f, 0.f, 0.f};

  // stage one half-tile piece: wave covers chunks {wave, wave+8} of 16
  auto stA = [&](int bi, int h, int kg) {
    const u16* g = Ab + (size_t)(h * 128 + wave * 8) * lda + kg;
    gld_lds16(g, &As[bi][h * 8192 + wave * 512]);
    gld_lds16(g + (size_t)64 * lda, &As[bi][h * 8192 + (wave + 8) * 512]);
  };
  auto stB = [&](int bi, int h, int kg) {
    const u16* g = Bb + (size_t)(h * 128 + wave * 8) * ldb + kg;
    gld_lds16(g, &Bs[bi][h * 8192 + wave * 512]);
    gld_lds16(g + (size_t)64 * ldb, &Bs[bi][h * 8192 + (wave + 8) * 512]);
  };

  const int nkt = K >> 6;  // call sites guarantee nkt >= 4

  // prologue: KT0 fully + KT1.{B.h0,B.h1,A.h0}; leave KT1 trio in flight
  stB(0, 0, 0);
  stB(0, 1, 0);
  stA(0, 0, 0);
  stA(0, 1, 0);
  stB(1, 0, 64);
  stB(1, 1, 64);
  stA(1, 0, 64);
  asm volatile("s_waitcnt vmcnt(6)" ::: "memory");
  __builtin_amdgcn_s_barrier();

  int buf = 0;
  for (int T = 0; T < nkt; ++T, buf ^= 1) {
    const int kc = T * 64;
    const bool sA1 = (T + 1) < nkt;
    const bool sN2 = (T + 2) < nkt;
    bf16x8 af[8], bv[4][2], ag[8];
    // ---- P0: q0 compute; ag (A@q1) reads interleaved under the MFMAs
#pragma unroll
    for (int n = 0; n < 4; ++n) {
      bv[n][0] = *(const bf16x8*)&Bs[buf][pbRow + n * 1024 + q0];
      bv[n][1] = *(const bf16x8*)&Bs[buf][pbRow + n * 1024 + q1];
    }
#pragma unroll
    for (int m = 0; m < 8; ++m)
      af[m] = *(const bf16x8*)&As[buf][paRow + m * 1024 + q0];
    if (sA1) stA(buf ^ 1, 1, kc + 64);
    asm volatile("s_waitcnt lgkmcnt(0)" ::: "memory");
    __builtin_amdgcn_sched_barrier(0);
    __builtin_amdgcn_s_setprio(1);
#pragma unroll
    for (int m = 0; m < 8; ++m) {
      MFMA16(af[m], bv[0][0], acc[m][0]);
      MFMA16(af[m], bv[1][0], acc[m][1]);
      MFMA16(af[m], bv[2][0], acc[m][2]);
      MFMA16(af[m], bv[3][0], acc[m][3]);
      ag[m] = *(const bf16x8*)&As[buf][paRow + m * 1024 + q1];
      __builtin_amdgcn_sched_group_barrier(0x008, 4, 0);  // 4 MFMA
      __builtin_amdgcn_sched_group_barrier(0x100, 1, 0);  // 1 DS_READ
    }
    __builtin_amdgcn_s_setprio(0);
    __builtin_amdgcn_s_barrier();
    // ---- P1: q1 compute (ag already serviced under P0 MFMAs)
    if (sN2) {
      stB(buf, 0, kc + 128);
      stB(buf, 1, kc + 128);
    }
    asm volatile("s_waitcnt lgkmcnt(0)" ::: "memory");
    __builtin_amdgcn_sched_barrier(0);
    __builtin_amdgcn_s_setprio(1);
#pragma unroll
    for (int m = 0; m < 8; ++m) {
      MFMA16(ag[m], bv[0][1], acc[m][0]);
      MFMA16(ag[m], bv[1][1], acc[m][1]);
      MFMA16(ag[m], bv[2][1], acc[m][2]);
      MFMA16(ag[m], bv[3][1], acc[m][3]);
    }
    __builtin_amdgcn_s_setprio(0);
    __builtin_amdgcn_s_barrier();
    // ---- P2: stage next A.h0 into freed As[buf], publish KT+1
    if (sN2) {
      stA(buf, 0, kc + 128);
      asm volatile("s_waitcnt vmcnt(6)" ::: "memory");
    } else if (sA1) {
      asm volatile("s_waitcnt vmcnt(0)" ::: "memory");
    }
    __builtin_amdgcn_s_barrier();
  }

  const int er = lane >> 4;
#pragma unroll
  for (int m = 0; m < 8; ++m)
#pragma unroll
    for (int n = 0; n < 4; ++n)
#pragma unroll
      for (int r = 0; r < 4; ++r)
        fc(m0 + wr * 128 + m * 16 + er * 4 + r, n0 + wc * 64 + n * 16 + fm,
           acc[m][n][r]);
}

// ---------------- epilogue functors ----------------
struct EQKV {
  u16* qb;
  u16* kb;
  float* vout;
  const float* bias;
  __device__ __forceinline__ void operator()(int m, int n, float v) const {
    v += bias[n];
    int b = m >> 11, l = m & 2047;
    int part = n >> 11, nn = n & 2047, h = nn >> 10, d = nn & 1023;
    size_t idx = ((size_t)((b << 1) + h) * 2048 + l) * 1024 + d;
    if (part == 0)
      qb[idx] = f2b(v);
    else if (part == 1)
      kb[idx] = f2b(v);
    else
      vout[idx] = v;
  }
};
struct EScoreB {
  u16* S;
  __device__ __forceinline__ void operator()(int m, int n, float v) const {
    S[((size_t)m << 11) + n] = f2b(v * 0.03125f + (n > m ? -1.0e9f : 0.0f));
  }
};
struct EBf16 {
  u16* o;
  int ld;
  __device__ __forceinline__ void operator()(int m, int n, float v) const {
    o[(size_t)m * ld + n] = f2b(v);
  }
};
struct EOut {
  float* o;
  const float* bias;
  __device__ __forceinline__ void operator()(int m, int n, float v) const {
    o[((size_t)m << 11) + n] = v + bias[n];
  }
};

__device__ __forceinline__ u16* spz(u16* sp0, u16* sp1, int z) {
  return (z < 4) ? sp0 + (size_t)z * 4194304 : sp1 + (size_t)(z - 4) * 4194304;
}

// ---------------- kernels ----------------
__global__ void __launch_bounds__(256) k_cast3(const float* x, const float* w1,
                                               const float* w2, u16* xb,
                                               u16* w1b, u16* w2b) {
  long i = (long)(blockIdx.x * 256 + threadIdx.x) * 4;
  const float* src;
  u16* dst;
  long off;
  if (i < 16777216L) {
    src = x; dst = xb; off = i;
  } else if (i < 16777216L + 12582912L) {
    src = w1; dst = w1b; off = i - 16777216L;
  } else {
    src = w2; dst = w2b; off = i - 16777216L - 12582912L;
  }
  float4 f = *(const float4*)(src + off);
  ushort4 o;
  o.x = f2b(f.x);
  o.y = f2b(f.y);
  o.z = f2b(f.z);
  o.w = f2b(f.w);
  *(ushort4*)(dst + off) = o;
}

// XCD-swizzled (T1): 768 wgs, 96/XCD -> each XCD owns 3 contiguous B-panels
// (3 MB, L2-resident) and streams A.
__global__ void __launch_bounds__(512, 2) k_qkv(const u16* xb, const u16* wb,
                                                const float* bias, u16* qb,
                                                u16* kb, float* vout) {
  int wg = blockIdx.x;
  int id2 = (wg & 7) * 96 + (wg >> 3);
  int nt = id2 >> 5;  // 0..23
  int mt = id2 & 31;  // 0..31
  gemm256_body(xb, 2048, wb, 2048, EQKV{qb, kb, vout, bias}, mt * 256,
               nt * 256, 2048);
}

__global__ void __launch_bounds__(256) k_rope(u16* qb, u16* kb, float* kout) {
  int l = blockIdx.x;
  int t = threadIdx.x;
  float lf = (float)l;
  const float c0 = (float)(-9.210340371976184 / 1024.0);
  float s0, c_0, s1, c_1;
  {
    float inv = __expf((float)(2 * t) * c0);
    __sincosf(lf * inv, &s0, &c_0);
    float inv2 = __expf((float)(2 * (t + 256)) * c0);
    __sincosf(lf * inv2, &s1, &c_1);
  }
#pragma unroll
  for (int bh = 0; bh < 8; ++bh) {
    size_t base = ((size_t)bh * 2048 + l) * 1024;
#pragma unroll
    for (int half = 0; half < 2; ++half) {
      int i = t + half * 256;
      float c = half ? c_1 : c_0;
      float s = half ? s1 : s0;
      float x1 = b2f(qb[base + i]), x2 = b2f(qb[base + 512 + i]);
      qb[base + i] = f2b(x1 * c - x2 * s);
      qb[base + 512 + i] = f2b(x1 * s + x2 * c);
      float y1 = b2f(kb[base + i]), y2 = b2f(kb[base + 512 + i]);
      float r1 = y1 * c - y2 * s, r2 = y1 * s + y2 * c;
      kb[base + i] = f2b(r1);
      kb[base + 512 + i] = f2b(r2);
      kout[base + i] = r1;
      kout[base + 512 + i] = r2;
    }
  }
}

__global__ void __launch_bounds__(256) k_transpose_v(const float* v, u16* vt) {
  __shared__ u16 tile[64][65];
  int bh = blockIdx.z;
  int d0 = blockIdx.x * 64, l0 = blockIdx.y * 64;
  const float* vb = v + (size_t)bh * 2048 * 1024;
  u16* vtb = vt + (size_t)bh * 1024 * 2048;
  int t = threadIdx.x;
  int c = t & 63, r4 = t >> 6;
#pragma unroll
  for (int r = 0; r < 16; ++r) {
    int row = r * 4 + r4;
    tile[row][c] = f2b(vb[(size_t)(l0 + row) * 1024 + d0 + c]);
  }
  __syncthreads();
#pragma unroll
  for (int r = 0; r < 16; ++r) {
    int drow = r * 4 + r4;
    vtb[(size_t)(d0 + drow) * 2048 + l0 + c] = tile[c][drow];
  }
}

__global__ void __launch_bounds__(256) k_score(const u16* qb, const u16* kb,
                                               u16* sp0, u16* sp1) {
  int m0 = blockIdx.y * 128, n0 = blockIdx.x * 128;
  if (n0 > m0) return;
  int z = blockIdx.z;
  const u16* q = qb + (size_t)z * 2048 * 1024;
  const u16* k = kb + (size_t)z * 2048 * 1024;
  gemm128_body(q, 1024, k, 1024, EScoreB{spz(sp0, sp1, z)}, m0, n0, 1024);
}

// in-place softmax; writes probs zero-padded out to a 256-col boundary so
// k_pv's 256-row tiles (Keff = m0+256) read fully-defined P everywhere.
__global__ void __launch_bounds__(256) k_softmax(u16* sp0, u16* sp1) {
  int l = blockIdx.x, z = blockIdx.y;
  u16* row = spz(sp0, sp1, z) + ((size_t)l << 11);
  int t = threadIdx.x;
  int jend = ((l >> 8) + 1) << 8;  // 256-granule
  __shared__ float red[4];
  float vals[8];
  float mx = -1e30f;
#pragma unroll
  for (int i = 0; i < 8; ++i) {
    int j = i * 256 + t;
    float v = (j <= l) ? b2f(row[j]) : -1e30f;
    vals[i] = v;
    mx = fmaxf(mx, v);
  }
#pragma unroll
  for (int off = 32; off; off >>= 1) mx = fmaxf(mx, __shfl_down(mx, off));
  if ((t & 63) == 0) red[t >> 6] = mx;
  __syncthreads();
  mx = fmaxf(fmaxf(red[0], red[1]), fmaxf(red[2], red[3]));
  __syncthreads();
  float sum = 0.f;
#pragma unroll
  for (int i = 0; i < 8; ++i) {
    int j = i * 256 + t;
    float e = (j <= l) ? __expf(vals[i] - mx) : 0.f;
    vals[i] = e;
    sum += e;
  }
#pragma unroll
  for (int off = 32; off; off >>= 1) sum += __shfl_down(sum, off);
  if ((t & 63) == 0) red[t >> 6] = sum;
  __syncthreads();
  sum = red[0] + red[1] + red[2] + red[3];
  float is = 1.0f / sum;
#pragma unroll
  for (int i = 0; i < 8; ++i) {
    int j = i * 256 + t;
    if (j < jend) row[j] = f2b(vals[i] * is);
  }
}

__global__ void __launch_bounds__(512, 2) k_pv(u16* sp0, u16* sp1,
                                               const u16* vt, u16* vh) {
  int z = blockIdx.z;
  int b = z >> 1, h = z & 1;
  int m0 = blockIdx.y * 256, n0 = blockIdx.x * 256;
  const u16* Pz = spz(sp0, sp1, z);
  const u16* vtb = vt + (size_t)z * 1024 * 2048;
  u16* outb = vh + (size_t)b * 2048 * 2048 + (size_t)h * 1024;
  int Keff = m0 + 256;  // causal: P zero-padded to 256 boundary by k_softmax
  gemm256_body(Pz, 2048, vtb, 2048, EBf16{outb, 2048}, m0, n0, Keff);
}

// XCD-swizzled: 256 wgs, 32/XCD -> each XCD owns one B-panel (1 MB).
__global__ void __launch_bounds__(512, 2) k_out(const u16* vh, const u16* w2,
                                                const float* bias, float* out) {
  int wg = blockIdx.x;
  int id2 = (wg & 7) * 32 + (wg >> 3);
  int nt = id2 >> 5;  // 0..7
  int mt = id2 & 31;  // 0..31
  gemm256_body(vh, 2048, w2, 2048, EOut{out, bias}, mt * 256, nt * 256, 2048);
}

// ---------------- launch ----------------
extern "C" void kernel_launch(void* const* d_in, const int* in_sizes, int n_in,
                              void* d_out, int out_size, void* d_ws,
                              size_t ws_size, hipStream_t stream) {
  const float* x = (const float*)d_in[0];
  const float* w1 = (const float*)d_in[2];
  const float* b1 = (const float*)d_in[3];
  const float* w2 = (const float*)d_in[4];
  const float* b2 = (const float*)d_in[5];
  float* out = (float*)d_out;
  float* kout = out + (size_t)16777216;
  float* vout = kout + (size_t)16777216;

  char* ws = (char*)d_ws;
  u16* xb = (u16*)ws;
  ws += (size_t)33554432;
  u16* w1b = (u16*)ws;
  ws += (size_t)25165824;
  u16* w2b = (u16*)ws;
  ws += (size_t)8388608;
  u16* qb = (u16*)ws;
  ws += (size_t)33554432;
  u16* kb = (u16*)ws;
  ws += (size_t)33554432;
  u16* vtb = (u16*)ws;
  ws += (size_t)33554432;
  u16* sp1 = (u16*)ws;
  u16* sp0 = xb;
  u16* vh = qb;

  k_cast3<<<32768, 256, 0, stream>>>(x, w1, w2, xb, w1b, w2b);
  k_qkv<<<768, 512, 0, stream>>>(xb, w1b, b1, qb, kb, vout);
  k_rope<<<2048, 256, 0, stream>>>(qb, kb, kout);
  k_transpose_v<<<dim3(16, 32, 8), 256, 0, stream>>>(vout, vtb);
  k_score<<<dim3(16, 16, 8), 256, 0, stream>>>(qb, kb, sp0, sp1);
  k_softmax<<<dim3(2048, 8), 256, 0, stream>>>(sp0, sp1);
  k_pv<<<dim3(4, 8, 8), 512, 0, stream>>>(sp0, sp1, vtb, vh);
  k_out<<<256, 512, 0, stream>>>(vh, w2b, b2, out);
}

// Round 3
// 782.921 us; speedup vs baseline: 1.1136x; 1.0316x over previous
//
#include <hip/hip_runtime.h>
#include <hip/hip_bf16.h>
#include <math.h>

typedef unsigned short u16;
typedef __attribute__((ext_vector_type(8))) __bf16 bf16x8;
typedef __attribute__((ext_vector_type(4))) float f32x4;

__device__ __forceinline__ u16 f2b(float f) {
  unsigned u = __builtin_bit_cast(unsigned, f);
  u += 0x7fffu + ((u >> 16) & 1u);
  return (u16)(u >> 16);
}
__device__ __forceinline__ float b2f(u16 h) {
  unsigned u = ((unsigned)h) << 16;
  return __builtin_bit_cast(float, u);
}

__device__ __forceinline__ void gld_lds16(const u16* g, u16* l) {
  __builtin_amdgcn_global_load_lds(
      (const __attribute__((address_space(1))) unsigned int*)g,
      (__attribute__((address_space(3))) unsigned int*)l, 16, 0, 0);
}

#define MFMA16(a, b, c) \
  c = __builtin_amdgcn_mfma_f32_16x16x32_bf16(a, b, c, 0, 0, 0)

// ---------------- 128x128 BT-form GEMM tile body (m97 structure) -----------
// used by k_score and k_pv (load-balance via many blocks beats per-block eff.)
template <class FC>
__device__ __forceinline__ void gemm128_body(const u16* A, int lda,
                                             const u16* B, int ldb, FC fc,
                                             int m0, int n0, int K) {
  __shared__ __align__(16) u16 As[128 * 64];
  __shared__ __align__(16) u16 Bs[128 * 64];
  const int tid = threadIdx.x;
  const int wave = tid >> 6;
  const int lane = tid & 63;
  const int srow = lane >> 3;
  const int scol = ((lane & 7) ^ srow) * 8;
  const int wm = (wave & 1) * 64;
  const int wn = (wave >> 1) * 64;
  const int fm = lane & 15;
  const int fs = fm & 7;

  const u16* Abase = A + (size_t)m0 * lda;
  const u16* Bbase = B + (size_t)n0 * ldb;
  const size_t aLane = (size_t)(wave * 8 + srow) * lda + scol;
  const size_t bLane = (size_t)(wave * 8 + srow) * ldb + scol;

  f32x4 acc[4][4];
#pragma unroll
  for (int i = 0; i < 4; ++i)
#pragma unroll
    for (int j = 0; j < 4; ++j) acc[i][j] = (f32x4){0.f, 0.f, 0.f, 0.f};

  for (int k0 = 0; k0 < K; k0 += 64) {
#pragma unroll
    for (int c = 0; c < 4; ++c) {
      gld_lds16(Abase + (aLane + (size_t)(c * 32) * lda + k0),
                &As[(c * 4 + wave) * 512]);
      gld_lds16(Bbase + (bLane + (size_t)(c * 32) * ldb + k0),
                &Bs[(c * 4 + wave) * 512]);
    }
    __syncthreads();
#pragma unroll
    for (int kk = 0; kk < 2; ++kk) {
      const int cb = kk * 4 + (lane >> 4);
      const int p8 = (cb ^ fs) * 8;
      bf16x8 af[4], bfr[4];
#pragma unroll
      for (int i = 0; i < 4; ++i)
        af[i] = *(const bf16x8*)&As[(wm + i * 16 + fm) * 64 + p8];
#pragma unroll
      for (int j = 0; j < 4; ++j)
        bfr[j] = *(const bf16x8*)&Bs[(wn + j * 16 + fm) * 64 + p8];
#pragma unroll
      for (int i = 0; i < 4; ++i)
#pragma unroll
        for (int j = 0; j < 4; ++j) MFMA16(af[i], bfr[j], acc[i][j]);
    }
    __syncthreads();
  }
  const int er = lane >> 4;
#pragma unroll
  for (int i = 0; i < 4; ++i)
#pragma unroll
    for (int j = 0; j < 4; ++j)
#pragma unroll
      for (int r = 0; r < 4; ++r) {
        int m = m0 + wm + i * 16 + er * 4 + r;
        int n = n0 + wn + j * 16 + fm;
        fc(m, n, acc[i][j][r]);
      }
}

// ---------------- 256x256 full-prefetch BT-form GEMM body ------------------
// 512 thr = 8 waves (2M x 4N), per-wave 128x64, BK=64, LDS 128KiB dbuf.
// Every ds_read rides under an MFMA cluster (zero exposed LDS drains):
//   tile T (buf=T&1): af[]/bv[][] were prefetched from buf during T-1.
//   PhA: stB2(T+2)->Bs[buf]; 32 MFMA q0 || ds_read ag(q1)->af[]; lgkm0; BAR1
//   PhB: stA2(T+2)->As[buf]; vmcnt(8) [T+1 landed, T+2's 8 in flight]; BAR2
//        32 MFMA q1 || ds_read af',bv' (T+1) from buf^1; lgkm0; BAR3
// Hazards: BAR1 publishes ag reads before stA2 overwrites As[buf]; BAR2
// publishes T+1 stages (all waves ran vmcnt(8)) before prefetch reads; BAR3
// publishes prefetch reads before T+1's stB2 hits Bs[buf^1]. lgkm0 always
// precedes the barrier that licenses an overwrite. Stages for tile X issue
// at tile X-2 (8 loads/wave/tile) -> steady-state vmcnt(8), never 0.
// Accumulation order identical to the 2-phase body (bit-identical results).
template <class FC>
__device__ __forceinline__ void gemm256_body(const u16* A, int lda,
                                             const u16* B, int ldb, FC fc,
                                             int m0, int n0, int K) {
  __shared__ __align__(16) u16 As[2][16384];
  __shared__ __align__(16) u16 Bs[2][16384];
  const int tid = threadIdx.x;
  const int wave = tid >> 6;
  const int lane = tid & 63;
  const int wr = wave >> 2;  // 0..1 (M)
  const int wc = wave & 3;   // 0..3 (N)
  const int fm = lane & 15;
  const int cb4 = lane >> 4;  // 0..3
  const int fs = fm & 7;
  const int srow = lane >> 3;
  const int scol = ((lane & 7) ^ srow) * 8;  // inverse-swizzled global col

  const u16* Ab = A + (size_t)(m0 + srow) * lda + scol;
  const u16* Bb = B + (size_t)(n0 + srow) * ldb + scol;

  const int paRow = (wr * 128 + fm) * 64;
  const int pbRow = (wc * 64 + fm) * 64;
  const int q0 = (cb4 ^ fs) * 8;  // phys chunk offset, kk0
  const int q1 = q0 ^ 32;         // kk1

  f32x4 acc[8][4];
#pragma unroll
  for (int m = 0; m < 8; ++m)
#pragma unroll
    for (int n = 0; n < 4; ++n) acc[m][n] = (f32x4){0.f, 0.f, 0.f, 0.f};

  // stage a full 256x64 half of A or B for one K-tile: 4 gld_lds per wave
  auto stA2 = [&](int bi, int kg) {
#pragma unroll
    for (int h = 0; h < 2; ++h) {
      const u16* g = Ab + (size_t)(h * 128 + wave * 8) * lda + kg;
      gld_lds16(g, &As[bi][h * 8192 + wave * 512]);
      gld_lds16(g + (size_t)64 * lda, &As[bi][h * 8192 + (wave + 8) * 512]);
    }
  };
  auto stB2 = [&](int bi, int kg) {
#pragma unroll
    for (int h = 0; h < 2; ++h) {
      const u16* g = Bb + (size_t)(h * 128 + wave * 8) * ldb + kg;
      gld_lds16(g, &Bs[bi][h * 8192 + wave * 512]);
      gld_lds16(g + (size_t)64 * ldb, &Bs[bi][h * 8192 + (wave + 8) * 512]);
    }
  };

  const int nkt = K >> 6;  // call sites guarantee nkt >= 4

  // prologue: stage T0 (8) + T1 (8); wait T0; pre-read T0 fragments
  stB2(0, 0);
  stA2(0, 0);
  stB2(1, 64);
  stA2(1, 64);
  asm volatile("s_waitcnt vmcnt(8)" ::: "memory");
  __builtin_amdgcn_s_barrier();
  bf16x8 af[8], bv[4][2];
#pragma unroll
  for (int m = 0; m < 8; ++m)
    af[m] = *(const bf16x8*)&As[0][paRow + m * 1024 + q0];
#pragma unroll
  for (int n = 0; n < 4; ++n) {
    bv[n][0] = *(const bf16x8*)&Bs[0][pbRow + n * 1024 + q0];
    bv[n][1] = *(const bf16x8*)&Bs[0][pbRow + n * 1024 + q1];
  }
  asm volatile("s_waitcnt lgkmcnt(0)" ::: "memory");
  __builtin_amdgcn_s_barrier();  // publish prologue reads before T0's stB2

  int buf = 0;
  for (int T = 0; T < nkt; ++T, buf ^= 1) {
    const int kc = T * 64;
    const bool sA1 = (T + 1) < nkt;
    const bool sN2 = (T + 2) < nkt;
    // ---- Phase A: MFMA q0 || ds_read ag(q1)->af ; stage B(T+2)
    if (sN2) stB2(buf, kc + 128);
    __builtin_amdgcn_sched_barrier(0);
    __builtin_amdgcn_s_setprio(1);
#pragma unroll
    for (int m = 0; m < 8; ++m) {
      MFMA16(af[m], bv[0][0], acc[m][0]);
      MFMA16(af[m], bv[1][0], acc[m][1]);
      MFMA16(af[m], bv[2][0], acc[m][2]);
      MFMA16(af[m], bv[3][0], acc[m][3]);
      af[m] = *(const bf16x8*)&As[buf][paRow + m * 1024 + q1];
      __builtin_amdgcn_sched_group_barrier(0x008, 4, 0);  // 4 MFMA
      __builtin_amdgcn_sched_group_barrier(0x100, 1, 0);  // 1 DS_READ
    }
    __builtin_amdgcn_s_setprio(0);
    asm volatile("s_waitcnt lgkmcnt(0)" ::: "memory");
    __builtin_amdgcn_s_barrier();  // BAR1: ag reads of As[buf] published
    // ---- Phase B: MFMA q1 || prefetch T+1 fragments from buf^1
    if (sN2) stA2(buf, kc + 128);
    __builtin_amdgcn_sched_barrier(0);
    if (sN2) {
      asm volatile("s_waitcnt vmcnt(8)" ::: "memory");
    } else if (sA1) {
      asm volatile("s_waitcnt vmcnt(0)" ::: "memory");
    }
    __builtin_amdgcn_s_barrier();  // BAR2: T+1 LDS data published
    __builtin_amdgcn_s_setprio(1);
    if (sA1) {
#pragma unroll
      for (int m = 0; m < 4; ++m) {
        MFMA16(af[m], bv[0][1], acc[m][0]);
        MFMA16(af[m], bv[1][1], acc[m][1]);
        MFMA16(af[m], bv[2][1], acc[m][2]);
        MFMA16(af[m], bv[3][1], acc[m][3]);
        af[m] = *(const bf16x8*)&As[buf ^ 1][paRow + m * 1024 + q0];
        bv[m][0] = *(const bf16x8*)&Bs[buf ^ 1][pbRow + m * 1024 + q0];
        __builtin_amdgcn_sched_group_barrier(0x008, 4, 0);  // 4 MFMA
        __builtin_amdgcn_sched_group_barrier(0x100, 2, 0);  // 2 DS_READ
      }
#pragma unroll
      for (int m = 4; m < 8; ++m) {
        MFMA16(af[m], bv[0][1], acc[m][0]);
        MFMA16(af[m], bv[1][1], acc[m][1]);
        MFMA16(af[m], bv[2][1], acc[m][2]);
        MFMA16(af[m], bv[3][1], acc[m][3]);
        af[m] = *(const bf16x8*)&As[buf ^ 1][paRow + m * 1024 + q0];
        __builtin_amdgcn_sched_group_barrier(0x008, 4, 0);  // 4 MFMA
        __builtin_amdgcn_sched_group_barrier(0x100, 1, 0);  // 1 DS_READ
      }
#pragma unroll
      for (int n = 0; n < 4; ++n)
        bv[n][1] = *(const bf16x8*)&Bs[buf ^ 1][pbRow + n * 1024 + q1];
    } else {
#pragma unroll
      for (int m = 0; m < 8; ++m) {
        MFMA16(af[m], bv[0][1], acc[m][0]);
        MFMA16(af[m], bv[1][1], acc[m][1]);
        MFMA16(af[m], bv[2][1], acc[m][2]);
        MFMA16(af[m], bv[3][1], acc[m][3]);
      }
    }
    __builtin_amdgcn_s_setprio(0);
    asm volatile("s_waitcnt lgkmcnt(0)" ::: "memory");
    __builtin_amdgcn_s_barrier();  // BAR3: buf^1 prefetch reads published
  }

  const int er = lane >> 4;
#pragma unroll
  for (int m = 0; m < 8; ++m)
#pragma unroll
    for (int n = 0; n < 4; ++n)
#pragma unroll
      for (int r = 0; r < 4; ++r)
        fc(m0 + wr * 128 + m * 16 + er * 4 + r, n0 + wc * 64 + n * 16 + fm,
           acc[m][n][r]);
}

// ---------------- epilogue functors ----------------
struct EQKV {
  u16* qb;
  u16* kb;
  float* vout;
  const float* bias;
  __device__ __forceinline__ void operator()(int m, int n, float v) const {
    v += bias[n];
    int b = m >> 11, l = m & 2047;
    int part = n >> 11, nn = n & 2047, h = nn >> 10, d = nn & 1023;
    size_t idx = ((size_t)((b << 1) + h) * 2048 + l) * 1024 + d;
    if (part == 0)
      qb[idx] = f2b(v);
    else if (part == 1)
      kb[idx] = f2b(v);
    else
      vout[idx] = v;
  }
};
struct EScoreB {
  u16* S;
  __device__ __forceinline__ void operator()(int m, int n, float v) const {
    S[((size_t)m << 11) + n] = f2b(v * 0.03125f + (n > m ? -1.0e9f : 0.0f));
  }
};
struct EBf16 {
  u16* o;
  int ld;
  __device__ __forceinline__ void operator()(int m, int n, float v) const {
    o[(size_t)m * ld + n] = f2b(v);
  }
};
struct EOut {
  float* o;
  const float* bias;
  __device__ __forceinline__ void operator()(int m, int n, float v) const {
    o[((size_t)m << 11) + n] = v + bias[n];
  }
};

__device__ __forceinline__ u16* spz(u16* sp0, u16* sp1, int z) {
  return (z < 4) ? sp0 + (size_t)z * 4194304 : sp1 + (size_t)(z - 4) * 4194304;
}

// ---------------- kernels ----------------
__global__ void __launch_bounds__(256) k_cast3(const float* x, const float* w1,
                                               const float* w2, u16* xb,
                                               u16* w1b, u16* w2b) {
  long i = (long)(blockIdx.x * 256 + threadIdx.x) * 4;
  const float* src;
  u16* dst;
  long off;
  if (i < 16777216L) {
    src = x; dst = xb; off = i;
  } else if (i < 16777216L + 12582912L) {
    src = w1; dst = w1b; off = i - 16777216L;
  } else {
    src = w2; dst = w2b; off = i - 16777216L - 12582912L;
  }
  float4 f = *(const float4*)(src + off);
  ushort4 o;
  o.x = f2b(f.x);
  o.y = f2b(f.y);
  o.z = f2b(f.z);
  o.w = f2b(f.w);
  *(ushort4*)(dst + off) = o;
}

__global__ void __launch_bounds__(512, 2) k_qkv(const u16* xb, const u16* wb,
                                                const float* bias, u16* qb,
                                                u16* kb, float* vout) {
  gemm256_body(xb, 2048, wb, 2048, EQKV{qb, kb, vout, bias}, blockIdx.y * 256,
               blockIdx.x * 256, 2048);
}

// vectorized: thread t handles d = 2t, 2t+1 (ushort2/float2 accesses);
// per-element math identical to the scalar version (same __expf/__sincosf).
__global__ void __launch_bounds__(256) k_rope(u16* qb, u16* kb, float* kout) {
  int l = blockIdx.x;
  int t = threadIdx.x;
  float lf = (float)l;
  const float c0 = (float)(-9.210340371976184 / 1024.0);  // -ln(1e4)/1024
  float sa, ca, sb, cb;
  {
    float inva = __expf((float)(4 * t) * c0);
    __sincosf(lf * inva, &sa, &ca);
    float invb = __expf((float)(4 * t + 2) * c0);
    __sincosf(lf * invb, &sb, &cb);
  }
  const int d = 2 * t;
#pragma unroll
  for (int bh = 0; bh < 8; ++bh) {
    size_t base = ((size_t)bh * 2048 + l) * 1024;
    ushort2 x1 = *(const ushort2*)&qb[base + d];
    ushort2 x2 = *(const ushort2*)&qb[base + 512 + d];
    float a1 = b2f(x1.x), a2 = b2f(x2.x);
    float b1 = b2f(x1.y), b2 = b2f(x2.y);
    ushort2 q1 = {f2b(a1 * ca - a2 * sa), f2b(b1 * cb - b2 * sb)};
    ushort2 q2 = {f2b(a1 * sa + a2 * ca), f2b(b1 * sb + b2 * cb)};
    *(ushort2*)&qb[base + d] = q1;
    *(ushort2*)&qb[base + 512 + d] = q2;
    ushort2 y1 = *(const ushort2*)&kb[base + d];
    ushort2 y2 = *(const ushort2*)&kb[base + 512 + d];
    float k1a = b2f(y1.x), k2a = b2f(y2.x);
    float k1b = b2f(y1.y), k2b = b2f(y2.y);
    float r1a = k1a * ca - k2a * sa, r2a = k1a * sa + k2a * ca;
    float r1b = k1b * cb - k2b * sb, r2b = k1b * sb + k2b * cb;
    ushort2 ka = {f2b(r1a), f2b(r1b)};
    ushort2 kc = {f2b(r2a), f2b(r2b)};
    *(ushort2*)&kb[base + d] = ka;
    *(ushort2*)&kb[base + 512 + d] = kc;
    *(float2*)&kout[base + d] = make_float2(r1a, r1b);
    *(float2*)&kout[base + 512 + d] = make_float2(r2a, r2b);
  }
}

__global__ void __launch_bounds__(256) k_transpose_v(const float* v, u16* vt) {
  __shared__ u16 tile[64][65];
  int bh = blockIdx.z;
  int d0 = blockIdx.x * 64, l0 = blockIdx.y * 64;
  const float* vb = v + (size_t)bh * 2048 * 1024;
  u16* vtb = vt + (size_t)bh * 1024 * 2048;
  int t = threadIdx.x;
  int c = t & 63, r4 = t >> 6;
#pragma unroll
  for (int r = 0; r < 16; ++r) {
    int row = r * 4 + r4;
    tile[row][c] = f2b(vb[(size_t)(l0 + row) * 1024 + d0 + c]);
  }
  __syncthreads();
#pragma unroll
  for (int r = 0; r < 16; ++r) {
    int drow = r * 4 + r4;
    vtb[(size_t)(d0 + drow) * 2048 + l0 + c] = tile[c][drow];
  }
}

__global__ void __launch_bounds__(256) k_score(const u16* qb, const u16* kb,
                                               u16* sp0, u16* sp1) {
  int m0 = blockIdx.y * 128, n0 = blockIdx.x * 128;
  if (n0 > m0) return;
  int z = blockIdx.z;
  const u16* q = qb + (size_t)z * 2048 * 1024;
  const u16* k = kb + (size_t)z * 2048 * 1024;
  gemm128_body(q, 1024, k, 1024, EScoreB{spz(sp0, sp1, z)}, m0, n0, 1024);
}

// in-place softmax; probs zero-padded out to a 256-col boundary (covers both
// the 128-tile k_pv Keff=m0+128 and any 256 tiling).
__global__ void __launch_bounds__(256) k_softmax(u16* sp0, u16* sp1) {
  int l = blockIdx.x, z = blockIdx.y;
  u16* row = spz(sp0, sp1, z) + ((size_t)l << 11);
  int t = threadIdx.x;
  int jend = ((l >> 8) + 1) << 8;
  __shared__ float red[4];
  float vals[8];
  float mx = -1e30f;
#pragma unroll
  for (int i = 0; i < 8; ++i) {
    int j = i * 256 + t;
    float v = (j <= l) ? b2f(row[j]) : -1e30f;
    vals[i] = v;
    mx = fmaxf(mx, v);
  }
#pragma unroll
  for (int off = 32; off; off >>= 1) mx = fmaxf(mx, __shfl_down(mx, off));
  if ((t & 63) == 0) red[t >> 6] = mx;
  __syncthreads();
  mx = fmaxf(fmaxf(red[0], red[1]), fmaxf(red[2], red[3]));
  __syncthreads();
  float sum = 0.f;
#pragma unroll
  for (int i = 0; i < 8; ++i) {
    int j = i * 256 + t;
    float e = (j <= l) ? __expf(vals[i] - mx) : 0.f;
    vals[i] = e;
    sum += e;
  }
#pragma unroll
  for (int off = 32; off; off >>= 1) sum += __shfl_down(sum, off);
  if ((t & 63) == 0) red[t >> 6] = sum;
  __syncthreads();
  sum = red[0] + red[1] + red[2] + red[3];
  float is = 1.0f / sum;
#pragma unroll
  for (int i = 0; i < 8; ++i) {
    int j = i * 256 + t;
    if (j < jend) row[j] = f2b(vals[i] * is);
  }
}

// 128-tile, 1024 blocks (4/CU): causal K-length imbalance averages out,
// unlike 256-tile (256 blocks = 1/CU, gated by the K=2048 straggler).
__global__ void __launch_bounds__(256) k_pv(u16* sp0, u16* sp1, const u16* vt,
                                            u16* vh) {
  int z = blockIdx.z;
  int b = z >> 1, h = z & 1;
  int m0 = blockIdx.y * 128, n0 = blockIdx.x * 128;
  const u16* Pz = spz(sp0, sp1, z);
  const u16* vtb = vt + (size_t)z * 1024 * 2048;
  u16* outb = vh + (size_t)b * 2048 * 2048 + (size_t)h * 1024;
  int Keff = m0 + 128;  // causal: P zero-padded past row end
  gemm128_body(Pz, 2048, vtb, 2048, EBf16{outb, 2048}, m0, n0, Keff);
}

__global__ void __launch_bounds__(512, 2) k_out(const u16* vh, const u16* w2,
                                                const float* bias, float* out) {
  gemm256_body(vh, 2048, w2, 2048, EOut{out, bias}, blockIdx.y * 256,
               blockIdx.x * 256, 2048);
}

// ---------------- launch ----------------
extern "C" void kernel_launch(void* const* d_in, const int* in_sizes, int n_in,
                              void* d_out, int out_size, void* d_ws,
                              size_t ws_size, hipStream_t stream) {
  const float* x = (const float*)d_in[0];
  const float* w1 = (const float*)d_in[2];
  const float* b1 = (const float*)d_in[3];
  const float* w2 = (const float*)d_in[4];
  const float* b2 = (const float*)d_in[5];
  float* out = (float*)d_out;
  float* kout = out + (size_t)16777216;
  float* vout = kout + (size_t)16777216;

  char* ws = (char*)d_ws;
  u16* xb = (u16*)ws;
  ws += (size_t)33554432;
  u16* w1b = (u16*)ws;
  ws += (size_t)25165824;
  u16* w2b = (u16*)ws;
  ws += (size_t)8388608;
  u16* qb = (u16*)ws;
  ws += (size_t)33554432;
  u16* kb = (u16*)ws;
  ws += (size_t)33554432;
  u16* vtb = (u16*)ws;
  ws += (size_t)33554432;
  u16* sp1 = (u16*)ws;
  u16* sp0 = xb;
  u16* vh = qb;

  k_cast3<<<32768, 256, 0, stream>>>(x, w1, w2, xb, w1b, w2b);
  k_qkv<<<dim3(24, 32), 512, 0, stream>>>(xb, w1b, b1, qb, kb, vout);
  k_rope<<<2048, 256, 0, stream>>>(qb, kb, kout);
  k_transpose_v<<<dim3(16, 32, 8), 256, 0, stream>>>(vout, vtb);
  k_score<<<dim3(16, 16, 8), 256, 0, stream>>>(qb, kb, sp0, sp1);
  k_softmax<<<dim3(2048, 8), 256, 0, stream>>>(sp0, sp1);
  k_pv<<<dim3(8, 16, 8), 256, 0, stream>>>(sp0, sp1, vtb, vh);
  k_out<<<dim3(8, 32), 512, 0, stream>>>(vh, w2b, b2, out);
}